// Round 12
// baseline (1682.311 us; speedup 1.0000x reference)
//
#include <hip/hip_runtime.h>
#include <math.h>

#define BB 8
#define NN 2048
#define KK 20

static __device__ __forceinline__ float lrelu(float h) {
    return h >= 0.f ? h : 0.2f * h;
}

// ---------------- transpose x (B,3,N) -> xt (B,N,4) padded ----------------
__global__ __launch_bounds__(256) void transpose_x(const float* __restrict__ x,
                                                   float* __restrict__ xt) {
    int t = blockIdx.x * 256 + threadIdx.x;
    if (t >= BB * NN) return;
    int b = t / NN, n = t % NN;
    const float* xb = x + (size_t)b * 3 * NN;
    float4 v;
    v.x = xb[n];
    v.y = xb[NN + n];
    v.z = xb[2 * NN + n];
    v.w = 0.f;
    reinterpret_cast<float4*>(xt)[t] = v;
}

// ---------------- per-point squared norm ----------------
__global__ __launch_bounds__(256) void xx_kernel(const float* __restrict__ F, int stride, int off,
                                                 int C, float* __restrict__ xx) {
    int t = blockIdx.x * 256 + threadIdx.x;
    if (t >= BB * NN) return;
    const float* p = F + (size_t)t * stride + off;
    float s = 0.f;
    for (int c = 0; c < C; ++c) { float v = p[c]; s += v * v; }
    xx[t] = s;
}

// ---------------- KNN partial top-20 over a 1024-col split (round-8 proven, no-spill) -------
// Grid: B * 64 rowgroups * 2 splits = 1024 blocks, 256 thr, 32 rows/block, TM=64 col tiles.
// Per tile: GEMM (broadcast mapping) -> keys vs row threshold -> LDS survivor queue ->
// dense insert-network. key = (sortable(pd) << 32) | ~idx -> exact jax top_k order.
template <int C>
__global__ __launch_bounds__(256, 4) void knn_kernel(const float* __restrict__ F, int stride,
                                                     int off, const float* __restrict__ xx,
                                                     unsigned long long* __restrict__ part) {
    constexpr int ROWS = 32, TM = 64, NSPLIT = 2, MSPAN = NN / NSPLIT;  // 1024
    constexpr int CK = (C >= 64) ? 32 : 4;           // K chunk staged at a time
    constexpr int SK = (C >= 64) ? 36 : 4;           // padded stride (floats)
    constexpr int NKT = (C + CK - 1) / CK;           // # K chunks
    constexpr int S4 = SK / 4;                       // float4 stride per row (9 or 1)
    constexpr int C4 = CK / 4;                       // valid float4 chunks (8 or 1)
    constexpr int QS = 66;                           // queue row stride (u64, pad vs banks)

    __shared__ __align__(16) float As[ROWS * SK];
    __shared__ __align__(16) float Bs[TM * SK];
    __shared__ float xxA[ROWS];
    __shared__ float xxB[TM];
    __shared__ __align__(16) unsigned long long qbuf[ROWS * QS];
    __shared__ unsigned int qcnt[ROWS];
    __shared__ unsigned long long thr[ROWS];

    const int t = threadIdx.x;
    const int split = blockIdx.x & (NSPLIT - 1);
    const int rg = (blockIdx.x >> 1) & 63;
    const int b = blockIdx.x >> 7;
    const int n0 = rg * ROWS;
    const float* Fb = F + (size_t)b * NN * stride + off;
    const float* xxb = xx + (size_t)b * NN;

    // sorted descending top-20 as u64 keys; 0 = empty (below any real key)
    unsigned long long tv[KK];
#pragma unroll
    for (int i = 0; i < KK; ++i) tv[i] = 0ull;

    const int rl = t & 3;    // gemm row-lane: rows rl+4j, j=0..7
    const int cl = t >> 2;   // gemm col-lane 0..63
    const int rr = t >> 3;   // topk row (0..31)
    const int sub = t & 7;   // topk sub-lane (0..7)

    if (t < ROWS) {
        xxA[t] = xxb[n0 + t];
        thr[t] = 0ull;
        qcnt[t] = 0u;
    }

    for (int mt = 0; mt < MSPAN / TM; ++mt) {
        const int m0 = split * MSPAN + mt * TM;
        float acc[8];
#pragma unroll
        for (int j = 0; j < 8; ++j) acc[j] = 0.f;

        for (int kt = 0; kt < NKT; ++kt) {
            __syncthreads();  // fences prev process-phase + queue reset (and init)
            if constexpr (C >= 64) {
                float4* As4w = reinterpret_cast<float4*>(As);
                float4* Bs4w = reinterpret_cast<float4*>(Bs);
                for (int i = t; i < ROWS * S4; i += 256) {
                    int r = i / S4, c4i = i % S4;
                    float4 v = make_float4(0.f, 0.f, 0.f, 0.f);
                    if (c4i < C4)
                        v = *reinterpret_cast<const float4*>(
                            Fb + (size_t)(n0 + r) * stride + kt * CK + 4 * c4i);
                    As4w[i] = v;
                }
                for (int i = t; i < TM * S4; i += 256) {
                    int r = i / S4, c4i = i % S4;
                    float4 v = make_float4(0.f, 0.f, 0.f, 0.f);
                    if (c4i < C4)
                        v = *reinterpret_cast<const float4*>(
                            Fb + (size_t)(m0 + r) * stride + kt * CK + 4 * c4i);
                    Bs4w[i] = v;
                }
            } else {
                // layer 1: xt rows are float4 with w=0 (contributes 0 to dot)
                if (t < ROWS)
                    reinterpret_cast<float4*>(As)[t] =
                        *reinterpret_cast<const float4*>(Fb + (size_t)(n0 + t) * 4);
                if (t < TM)
                    reinterpret_cast<float4*>(Bs)[t] =
                        *reinterpret_cast<const float4*>(Fb + (size_t)(m0 + t) * 4);
            }
            if (kt == 0 && t < TM) xxB[t] = xxb[m0 + t];
            __syncthreads();

            const float4* As4 = reinterpret_cast<const float4*>(As);
            const float4* Bs4 = reinterpret_cast<const float4*>(Bs);
#pragma unroll
            for (int c4 = 0; c4 < C4; ++c4) {
                float4 b0 = Bs4[cl * S4 + c4];
#pragma unroll
                for (int j = 0; j < 8; ++j) {
                    float4 a = As4[(rl + 4 * j) * S4 + c4];  // 16-lane broadcast
                    acc[j] += a.x * b0.x;
                    acc[j] += a.y * b0.y;
                    acc[j] += a.z * b0.z;
                    acc[j] += a.w * b0.w;
                }
            }
        }

        // ---- append phase: build keys from GEMM regs, filter vs row threshold ----
#pragma unroll
        for (int j = 0; j < 8; ++j) {
            int r = rl + 4 * j;
            float v = (2.f * acc[j] - xxA[r]) - xxB[cl];
            unsigned int u = __float_as_uint(v);
            unsigned int sv = u ^ (unsigned int)(((int)u >> 31) | 0x80000000);
            unsigned long long kc = ((unsigned long long)sv << 32) | (unsigned int)(~(m0 + cl));
            unsigned long long th = thr[r];
            if (th == 0ull) {
                qbuf[r * QS + cl] = kc;  // warm-up: everything survives, direct slot
            } else if (kc > th) {
                unsigned int pos = atomicAdd(&qcnt[r], 1u);
                qbuf[r * QS + pos] = kc;
            }
        }
        __syncthreads();  // queue visible

        // ---- process phase: 8 lanes/row pop dense survivors into sorted-20 lists ----
        {
            unsigned long long throw_ = thr[rr];
            int n = (throw_ == 0ull) ? TM : (int)qcnt[rr];
            for (int s = 0; s < TM / 8; ++s) {
                int qi = s * 8 + sub;
                bool act = qi < n;
                if (__ballot(act) == 0ull) break;
                unsigned long long c = act ? qbuf[rr * QS + qi] : 0ull;
                if (c > tv[KK - 1]) {
#pragma unroll
                    for (int sl = KK - 1; sl >= 1; --sl) {
                        bool shs = c > tv[sl];
                        bool shp = c > tv[sl - 1];
                        unsigned long long tmp = shp ? tv[sl - 1] : c;
                        tv[sl] = shs ? tmp : tv[sl];
                    }
                    tv[0] = (c > tv[0]) ? c : tv[0];
                }
            }
            // tighten row threshold = max over 8 lanes of 20th-best; reset queue
            unsigned long long m19 = tv[KK - 1];
#pragma unroll
            for (int d = 1; d < 8; d <<= 1) {
                unsigned long long o = __shfl_xor(m19, d);
                m19 = (o > m19) ? o : m19;
            }
            if (sub == 0) {
                thr[rr] = m19;
                qcnt[rr] = 0u;
            }
        }
        // next tile's first __syncthreads() fences queue reset/threshold
    }

    // merge 8 sorted lists per row (8-lane shfl max-extract), write u64 list
    unsigned long long* op =
        part + (((size_t)b * NN + n0 + rr) * NSPLIT + split) * KK;
    for (int s = 0; s < KK; ++s) {
        unsigned long long m = tv[0];
#pragma unroll
        for (int d = 1; d < 8; d <<= 1) {
            unsigned long long o = __shfl_xor(m, d);
            m = (o > m) ? o : m;
        }
        if (sub == 0) op[s] = m;
        bool win = (tv[0] == m);
#pragma unroll
        for (int q = 0; q < KK - 1; ++q) tv[q] = win ? tv[q + 1] : tv[q];
        tv[KK - 1] = win ? 0ull : tv[KK - 1];
    }
}

// ---------------- merge 2 per-split sorted lists per row -> final indices ----------------
__global__ __launch_bounds__(256) void knn_merge(const unsigned long long* __restrict__ part,
                                                 int* __restrict__ idxOut) {
    int t = blockIdx.x * 256 + threadIdx.x;  // 2 lanes per row
    int q = t & 1, row = t >> 1;
    if (row >= BB * NN) return;
    unsigned long long k[KK];
    const unsigned long long* lp = part + ((size_t)row * 2 + q) * KK;
#pragma unroll
    for (int s = 0; s < KK; ++s) k[s] = lp[s];
    int* op = idxOut + (size_t)row * KK;
    for (int s = 0; s < KK; ++s) {
        unsigned long long m = k[0];
        unsigned long long o1 = __shfl_xor(m, 1);
        m = (o1 > m) ? o1 : m;
        if (q == 0) op[s] = (int)(~(unsigned int)m);
        bool win = (k[0] == m);
#pragma unroll
        for (int qq = 0; qq < KK - 1; ++qq) k[qq] = win ? k[qq + 1] : k[qq];
        k[KK - 1] = win ? 0ull : k[KK - 1];
    }
}

// ------- 128x128 tiled fp32 GEMM with fused Wa/(Wb-Wa) transform:
// out[M, 2O]: out[:,o]=F·Wa[o]  out[:,O+o]=F·(Wb[o]-Wa[o]);  W is (O, 2K) raw.
__global__ __launch_bounds__(256) void gemm_yz(const float* __restrict__ F, int stride, int off,
                                               const float* __restrict__ W, int K, int O,
                                               float* __restrict__ out) {
    __shared__ float As[128 * 36];
    __shared__ float Ws[128 * 36];
    const int t = threadIdx.x;
    const int row0 = blockIdx.x * 128;
    const int col0 = blockIdx.y * 128;
    const int OC = 2 * O;
    float acc[8][8];
#pragma unroll
    for (int i = 0; i < 8; ++i)
#pragma unroll
        for (int j = 0; j < 8; ++j) acc[i][j] = 0.f;

    for (int kt = 0; kt < K; kt += 32) {
        __syncthreads();
        for (int i = t; i < 128 * 32; i += 256) {
            int r = i >> 5, c = i & 31;
            int k = kt + c;
            As[r * 36 + c] = (k < K) ? F[(size_t)(row0 + r) * stride + off + k] : 0.f;
            float wv = 0.f;
            if (k < K) {
                int o2 = col0 + r;
                if (o2 < O) wv = W[(size_t)o2 * 2 * K + k];
                else wv = W[(size_t)(o2 - O) * 2 * K + K + k] - W[(size_t)(o2 - O) * 2 * K + k];
            }
            Ws[r * 36 + c] = wv;
        }
        __syncthreads();
        const int r0 = t & 15, c0 = t >> 4;
        const float4* As4 = reinterpret_cast<const float4*>(As);
        const float4* Ws4 = reinterpret_cast<const float4*>(Ws);
#pragma unroll
        for (int k4 = 0; k4 < 8; ++k4) {
            float4 a[8], w[8];
#pragma unroll
            for (int i = 0; i < 8; ++i) a[i] = As4[(r0 + 16 * i) * 9 + k4];
#pragma unroll
            for (int j = 0; j < 8; ++j) w[j] = Ws4[(c0 + 16 * j) * 9 + k4];
#pragma unroll
            for (int i = 0; i < 8; ++i)
#pragma unroll
                for (int j = 0; j < 8; ++j) {
                    acc[i][j] += a[i].x * w[j].x;
                    acc[i][j] += a[i].y * w[j].y;
                    acc[i][j] += a[i].z * w[j].z;
                    acc[i][j] += a[i].w * w[j].w;
                }
        }
    }
    const int r0 = t & 15, c0 = t >> 4;
#pragma unroll
    for (int i = 0; i < 8; ++i)
#pragma unroll
        for (int j = 0; j < 8; ++j)
            out[(size_t)(row0 + r0 + 16 * i) * OC + col0 + c0 + 16 * j] = acc[i][j];
}

// ---------------- neighbor gather-max + affine + lrelu -> cat column block ----------------
__global__ __launch_bounds__(256) void neighbor_max(const float* __restrict__ yz,
                                                    const int* __restrict__ idx,
                                                    const float* __restrict__ g,
                                                    const float* __restrict__ bia, int O,
                                                    int outOff, float* __restrict__ cat) {
    int t = blockIdx.x * 256 + threadIdx.x;
    int og = O >> 2;
    if (t >= BB * NN * og) return;
    int o4 = t % og;
    int pn = t / og;
    int bbase = (pn >> 11) << 11;  // batch base row
    const int* ip = idx + (size_t)pn * KK;
    int O2 = O * 2;
    float mx = -INFINITY, my = -INFINITY, mz = -INFINITY, mw = -INFINITY;
    for (int j = 0; j < KK; ++j) {
        int nb = ip[j];
        const float4 v =
            *reinterpret_cast<const float4*>(yz + (size_t)(bbase + nb) * O2 + (o4 << 2));
        mx = fmaxf(mx, v.x); my = fmaxf(my, v.y); mz = fmaxf(mz, v.z); mw = fmaxf(mw, v.w);
    }
    const float4 z = *reinterpret_cast<const float4*>(yz + (size_t)pn * O2 + O + (o4 << 2));
    int o = o4 << 2;
    const float inv = 1.f / sqrtf(1.f + 1e-5f);
    float4 r;
    r.x = lrelu((mx + z.x) * (g[o + 0] * inv) + bia[o + 0]);
    r.y = lrelu((my + z.y) * (g[o + 1] * inv) + bia[o + 1]);
    r.z = lrelu((mz + z.z) * (g[o + 2] * inv) + bia[o + 2]);
    r.w = lrelu((mw + z.w) * (g[o + 3] * inv) + bia[o + 3]);
    *reinterpret_cast<float4*>(cat + (size_t)pn * 512 + outOff + o) = r;
}

// ---------------- final conv (K=512 -> 1024) + affine + lrelu + max over 128-point tile -----
// round-8 body/grid; ONLY change: red aliased onto As/Ws block (45.5KB -> 36.9KB LDS,
// 3 -> 4 blocks/CU) with one extra barrier after the K-loop.
__global__ __launch_bounds__(256) void final_gemm_max(const float* __restrict__ A,
                                                      const float* __restrict__ W,
                                                      const float* __restrict__ g,
                                                      const float* __restrict__ bia,
                                                      float* __restrict__ partial) {
    __shared__ __align__(16) float smem[2 * 128 * 36];
    float* As = smem;
    float* Ws = smem + 128 * 36;
    float* red = smem;  // alias; only touched after post-loop barrier
    const int t = threadIdx.x;
    const int row0 = blockIdx.x * 128;  // global point row (batches contiguous)
    const int col0 = blockIdx.y * 128;
    float acc[8][8];
#pragma unroll
    for (int i = 0; i < 8; ++i)
#pragma unroll
        for (int j = 0; j < 8; ++j) acc[i][j] = 0.f;

    for (int kt = 0; kt < 512; kt += 32) {
        __syncthreads();
        for (int i = t; i < 128 * 32; i += 256) {
            int r = i >> 5, c = i & 31;
            int k = kt + c;
            As[r * 36 + c] = A[(size_t)(row0 + r) * 512 + k];
            Ws[r * 36 + c] = W[(size_t)(col0 + r) * 512 + k];
        }
        __syncthreads();
        const int r0 = t & 15, c0 = t >> 4;
        const float4* As4 = reinterpret_cast<const float4*>(As);
        const float4* Ws4 = reinterpret_cast<const float4*>(Ws);
#pragma unroll
        for (int k4 = 0; k4 < 8; ++k4) {
            float4 a[8], w[8];
#pragma unroll
            for (int i = 0; i < 8; ++i) a[i] = As4[(r0 + 16 * i) * 9 + k4];
#pragma unroll
            for (int j = 0; j < 8; ++j) w[j] = Ws4[(c0 + 16 * j) * 9 + k4];
#pragma unroll
            for (int i = 0; i < 8; ++i)
#pragma unroll
                for (int j = 0; j < 8; ++j) {
                    acc[i][j] += a[i].x * w[j].x;
                    acc[i][j] += a[i].y * w[j].y;
                    acc[i][j] += a[i].z * w[j].z;
                    acc[i][j] += a[i].w * w[j].w;
                }
        }
    }
    __syncthreads();  // all As/Ws reads done before red alias is written
    const int r0 = t & 15, c0 = t >> 4;
    const float inv = 1.f / sqrtf(1.f + 1e-5f);
#pragma unroll
    for (int j = 0; j < 8; ++j) {
        int o = col0 + c0 + 16 * j;
        float s = g[o] * inv;
        float bb = bia[o];
        float cm = -INFINITY;
#pragma unroll
        for (int i = 0; i < 8; ++i) {
            float h = acc[i][j] * s + bb;
            h = lrelu(h);
            cm = fmaxf(cm, h);
        }
        red[r0 * 132 + c0 + 16 * j] = cm;
    }
    __syncthreads();
    if (t < 128) {
        float m = -INFINITY;
        for (int q = 0; q < 16; ++q) m = fmaxf(m, red[q * 132 + t]);
        partial[(size_t)blockIdx.x * 1024 + col0 + t] = m;
    }
}

__global__ __launch_bounds__(256) void final_reduce(const float* __restrict__ partial,
                                                    float* __restrict__ out) {
    int t = blockIdx.x * 256 + threadIdx.x;
    if (t >= BB * 1024) return;
    int b = t >> 10, o = t & 1023;
    float m = -INFINITY;
    for (int q = 0; q < 16; ++q) m = fmaxf(m, partial[(size_t)(b * 16 + q) * 1024 + o]);
    out[t] = m;
}

extern "C" void kernel_launch(void* const* d_in, const int* in_sizes, int n_in, void* d_out,
                              int out_size, void* d_ws, size_t ws_size, hipStream_t stream) {
    const float* x  = (const float*)d_in[0];
    const float* W1 = (const float*)d_in[1];
    const float* W2 = (const float*)d_in[2];
    const float* W3 = (const float*)d_in[3];
    const float* W4 = (const float*)d_in[4];
    const float* W5 = (const float*)d_in[5];
    const float* g1 = (const float*)d_in[6];  const float* b1 = (const float*)d_in[7];
    const float* g2 = (const float*)d_in[8];  const float* b2 = (const float*)d_in[9];
    const float* g3 = (const float*)d_in[10]; const float* b3 = (const float*)d_in[11];
    const float* g4 = (const float*)d_in[12]; const float* b4 = (const float*)d_in[13];
    const float* g5 = (const float*)d_in[14]; const float* b5 = (const float*)d_in[15];

    float* ws   = (float*)d_ws;
    float* xt   = ws;                      // B*N*4          = 65536
    float* cat  = xt + 65536;              // B*N*512        = 8388608
    float* yz   = cat + 8388608;           // B*N*512        = 8388608
    float* xxb  = yz + 8388608;            // B*N            = 16384
    int*   idxb = (int*)(xxb + 16384);     // B*N*20         = 327680
    float* part = (float*)(idxb + 327680); // 128*1024       = 131072
    // knn partial lists alias yz (live only between knn_kernel and knn_merge;
    // yz is written by gemm_yz strictly after knn_merge each layer)
    unsigned long long* knnp = (unsigned long long*)yz;  // 16384*2*20 u64 = 5.2 MB

    dim3 blk(256);

    transpose_x<<<dim3(64), blk, 0, stream>>>(x, xt);

    // ---- layer 1: C=3 (xt, stride 4), O=64 -> cat[0..64)
    xx_kernel<<<dim3(64), blk, 0, stream>>>(xt, 4, 0, 3, xxb);
    knn_kernel<3><<<dim3(1024), blk, 0, stream>>>(xt, 4, 0, xxb, knnp);
    knn_merge<<<dim3(128), blk, 0, stream>>>(knnp, idxb);
    gemm_yz<<<dim3(128, 1), blk, 0, stream>>>(xt, 4, 0, W1, 3, 64, yz);
    neighbor_max<<<dim3(1024), blk, 0, stream>>>(yz, idxb, g1, b1, 64, 0, cat);

    // ---- layer 2: C=64 (cat off 0), O=64 -> cat[64..128)
    xx_kernel<<<dim3(64), blk, 0, stream>>>(cat, 512, 0, 64, xxb);
    knn_kernel<64><<<dim3(1024), blk, 0, stream>>>(cat, 512, 0, xxb, knnp);
    knn_merge<<<dim3(128), blk, 0, stream>>>(knnp, idxb);
    gemm_yz<<<dim3(128, 1), blk, 0, stream>>>(cat, 512, 0, W2, 64, 64, yz);
    neighbor_max<<<dim3(1024), blk, 0, stream>>>(yz, idxb, g2, b2, 64, 64, cat);

    // ---- layer 3: C=64 (cat off 64), O=128 -> cat[128..256)
    xx_kernel<<<dim3(64), blk, 0, stream>>>(cat, 512, 64, 64, xxb);
    knn_kernel<64><<<dim3(1024), blk, 0, stream>>>(cat, 512, 64, xxb, knnp);
    knn_merge<<<dim3(128), blk, 0, stream>>>(knnp, idxb);
    gemm_yz<<<dim3(128, 2), blk, 0, stream>>>(cat, 512, 64, W3, 64, 128, yz);
    neighbor_max<<<dim3(2048), blk, 0, stream>>>(yz, idxb, g3, b3, 128, 128, cat);

    // ---- layer 4: C=128 (cat off 128), O=256 -> cat[256..512)
    xx_kernel<<<dim3(64), blk, 0, stream>>>(cat, 512, 128, 128, xxb);
    knn_kernel<128><<<dim3(1024), blk, 0, stream>>>(cat, 512, 128, xxb, knnp);
    knn_merge<<<dim3(128), blk, 0, stream>>>(knnp, idxb);
    gemm_yz<<<dim3(128, 4), blk, 0, stream>>>(cat, 512, 128, W4, 128, 256, yz);
    neighbor_max<<<dim3(4096), blk, 0, stream>>>(yz, idxb, g4, b4, 256, 256, cat);

    // ---- final: 512 -> 1024 conv + lrelu + global max over N
    final_gemm_max<<<dim3(128, 8), blk, 0, stream>>>(cat, W5, g5, b5, part);
    final_reduce<<<dim3(32), blk, 0, stream>>>(part, (float*)d_out);
}

// Round 13
// 1418.224 us; speedup vs baseline: 1.1862x; 1.1862x over previous
//
#include <hip/hip_runtime.h>
#include <math.h>

#define BB 8
#define NN 2048
#define KK 20

static __device__ __forceinline__ float lrelu(float h) {
    return h >= 0.f ? h : 0.2f * h;
}

// ---------------- transpose x (B,3,N) -> xt (B,N,4) padded ----------------
__global__ __launch_bounds__(256) void transpose_x(const float* __restrict__ x,
                                                   float* __restrict__ xt) {
    int t = blockIdx.x * 256 + threadIdx.x;
    if (t >= BB * NN) return;
    int b = t / NN, n = t % NN;
    const float* xb = x + (size_t)b * 3 * NN;
    float4 v;
    v.x = xb[n];
    v.y = xb[NN + n];
    v.z = xb[2 * NN + n];
    v.w = 0.f;
    reinterpret_cast<float4*>(xt)[t] = v;
}

// ---------------- per-point squared norm ----------------
__global__ __launch_bounds__(256) void xx_kernel(const float* __restrict__ F, int stride, int off,
                                                 int C, float* __restrict__ xx) {
    int t = blockIdx.x * 256 + threadIdx.x;
    if (t >= BB * NN) return;
    const float* p = F + (size_t)t * stride + off;
    float s = 0.f;
    for (int c = 0; c < C; ++c) { float v = p[c]; s += v * v; }
    xx[t] = s;
}

// ---------------- KNN partial top-20 over a 1024-col split (round-8 proven, no-spill) -------
// Grid: B * 64 rowgroups * 2 splits = 1024 blocks, 256 thr, 32 rows/block, TM=64 col tiles.
// Per tile: GEMM (broadcast mapping) -> keys vs row threshold -> LDS survivor queue ->
// dense insert-network. key = (sortable(pd) << 32) | ~idx -> exact jax top_k order.
template <int C>
__global__ __launch_bounds__(256, 4) void knn_kernel(const float* __restrict__ F, int stride,
                                                     int off, const float* __restrict__ xx,
                                                     unsigned long long* __restrict__ part) {
    constexpr int ROWS = 32, TM = 64, NSPLIT = 2, MSPAN = NN / NSPLIT;  // 1024
    constexpr int CK = (C >= 64) ? 32 : 4;           // K chunk staged at a time
    constexpr int SK = (C >= 64) ? 36 : 4;           // padded stride (floats)
    constexpr int NKT = (C + CK - 1) / CK;           // # K chunks
    constexpr int S4 = SK / 4;                       // float4 stride per row (9 or 1)
    constexpr int C4 = CK / 4;                       // valid float4 chunks (8 or 1)
    constexpr int QS = 66;                           // queue row stride (u64, pad vs banks)

    __shared__ __align__(16) float As[ROWS * SK];
    __shared__ __align__(16) float Bs[TM * SK];
    __shared__ float xxA[ROWS];
    __shared__ float xxB[TM];
    __shared__ __align__(16) unsigned long long qbuf[ROWS * QS];
    __shared__ unsigned int qcnt[ROWS];
    __shared__ unsigned long long thr[ROWS];

    const int t = threadIdx.x;
    const int split = blockIdx.x & (NSPLIT - 1);
    const int rg = (blockIdx.x >> 1) & 63;
    const int b = blockIdx.x >> 7;
    const int n0 = rg * ROWS;
    const float* Fb = F + (size_t)b * NN * stride + off;
    const float* xxb = xx + (size_t)b * NN;

    // sorted descending top-20 as u64 keys; 0 = empty (below any real key)
    unsigned long long tv[KK];
#pragma unroll
    for (int i = 0; i < KK; ++i) tv[i] = 0ull;

    const int rl = t & 3;    // gemm row-lane: rows rl+4j, j=0..7
    const int cl = t >> 2;   // gemm col-lane 0..63
    const int rr = t >> 3;   // topk row (0..31)
    const int sub = t & 7;   // topk sub-lane (0..7)

    if (t < ROWS) {
        xxA[t] = xxb[n0 + t];
        thr[t] = 0ull;
        qcnt[t] = 0u;
    }

    for (int mt = 0; mt < MSPAN / TM; ++mt) {
        const int m0 = split * MSPAN + mt * TM;
        float acc[8];
#pragma unroll
        for (int j = 0; j < 8; ++j) acc[j] = 0.f;

        for (int kt = 0; kt < NKT; ++kt) {
            __syncthreads();  // fences prev process-phase + queue reset (and init)
            if constexpr (C >= 64) {
                float4* As4w = reinterpret_cast<float4*>(As);
                float4* Bs4w = reinterpret_cast<float4*>(Bs);
                for (int i = t; i < ROWS * S4; i += 256) {
                    int r = i / S4, c4i = i % S4;
                    float4 v = make_float4(0.f, 0.f, 0.f, 0.f);
                    if (c4i < C4)
                        v = *reinterpret_cast<const float4*>(
                            Fb + (size_t)(n0 + r) * stride + kt * CK + 4 * c4i);
                    As4w[i] = v;
                }
                for (int i = t; i < TM * S4; i += 256) {
                    int r = i / S4, c4i = i % S4;
                    float4 v = make_float4(0.f, 0.f, 0.f, 0.f);
                    if (c4i < C4)
                        v = *reinterpret_cast<const float4*>(
                            Fb + (size_t)(m0 + r) * stride + kt * CK + 4 * c4i);
                    Bs4w[i] = v;
                }
            } else {
                // layer 1: xt rows are float4 with w=0 (contributes 0 to dot)
                if (t < ROWS)
                    reinterpret_cast<float4*>(As)[t] =
                        *reinterpret_cast<const float4*>(Fb + (size_t)(n0 + t) * 4);
                if (t < TM)
                    reinterpret_cast<float4*>(Bs)[t] =
                        *reinterpret_cast<const float4*>(Fb + (size_t)(m0 + t) * 4);
            }
            if (kt == 0 && t < TM) xxB[t] = xxb[m0 + t];
            __syncthreads();

            const float4* As4 = reinterpret_cast<const float4*>(As);
            const float4* Bs4 = reinterpret_cast<const float4*>(Bs);
#pragma unroll
            for (int c4 = 0; c4 < C4; ++c4) {
                float4 b0 = Bs4[cl * S4 + c4];
#pragma unroll
                for (int j = 0; j < 8; ++j) {
                    float4 a = As4[(rl + 4 * j) * S4 + c4];  // 16-lane broadcast
                    acc[j] += a.x * b0.x;
                    acc[j] += a.y * b0.y;
                    acc[j] += a.z * b0.z;
                    acc[j] += a.w * b0.w;
                }
            }
        }

        // ---- append phase: build keys from GEMM regs, filter vs row threshold ----
#pragma unroll
        for (int j = 0; j < 8; ++j) {
            int r = rl + 4 * j;
            float v = (2.f * acc[j] - xxA[r]) - xxB[cl];
            unsigned int u = __float_as_uint(v);
            unsigned int sv = u ^ (unsigned int)(((int)u >> 31) | 0x80000000);
            unsigned long long kc = ((unsigned long long)sv << 32) | (unsigned int)(~(m0 + cl));
            unsigned long long th = thr[r];
            if (th == 0ull) {
                qbuf[r * QS + cl] = kc;  // warm-up: everything survives, direct slot
            } else if (kc > th) {
                unsigned int pos = atomicAdd(&qcnt[r], 1u);
                qbuf[r * QS + pos] = kc;
            }
        }
        __syncthreads();  // queue visible

        // ---- process phase: 8 lanes/row pop dense survivors into sorted-20 lists ----
        {
            unsigned long long throw_ = thr[rr];
            int n = (throw_ == 0ull) ? TM : (int)qcnt[rr];
            for (int s = 0; s < TM / 8; ++s) {
                int qi = s * 8 + sub;
                bool act = qi < n;
                if (__ballot(act) == 0ull) break;
                unsigned long long c = act ? qbuf[rr * QS + qi] : 0ull;
                if (c > tv[KK - 1]) {
#pragma unroll
                    for (int sl = KK - 1; sl >= 1; --sl) {
                        bool shs = c > tv[sl];
                        bool shp = c > tv[sl - 1];
                        unsigned long long tmp = shp ? tv[sl - 1] : c;
                        tv[sl] = shs ? tmp : tv[sl];
                    }
                    tv[0] = (c > tv[0]) ? c : tv[0];
                }
            }
            // tighten row threshold = max over 8 lanes of 20th-best; reset queue
            unsigned long long m19 = tv[KK - 1];
#pragma unroll
            for (int d = 1; d < 8; d <<= 1) {
                unsigned long long o = __shfl_xor(m19, d);
                m19 = (o > m19) ? o : m19;
            }
            if (sub == 0) {
                thr[rr] = m19;
                qcnt[rr] = 0u;
            }
        }
        // next tile's first __syncthreads() fences queue reset/threshold
    }

    // merge 8 sorted lists per row (8-lane shfl max-extract), write u64 list
    unsigned long long* op =
        part + (((size_t)b * NN + n0 + rr) * NSPLIT + split) * KK;
    for (int s = 0; s < KK; ++s) {
        unsigned long long m = tv[0];
#pragma unroll
        for (int d = 1; d < 8; d <<= 1) {
            unsigned long long o = __shfl_xor(m, d);
            m = (o > m) ? o : m;
        }
        if (sub == 0) op[s] = m;
        bool win = (tv[0] == m);
#pragma unroll
        for (int q = 0; q < KK - 1; ++q) tv[q] = win ? tv[q + 1] : tv[q];
        tv[KK - 1] = win ? 0ull : tv[KK - 1];
    }
}

// ---------------- merge 2 per-split sorted lists per row -> final indices ----------------
__global__ __launch_bounds__(256) void knn_merge(const unsigned long long* __restrict__ part,
                                                 int* __restrict__ idxOut) {
    int t = blockIdx.x * 256 + threadIdx.x;  // 2 lanes per row
    int q = t & 1, row = t >> 1;
    if (row >= BB * NN) return;
    unsigned long long k[KK];
    const unsigned long long* lp = part + ((size_t)row * 2 + q) * KK;
#pragma unroll
    for (int s = 0; s < KK; ++s) k[s] = lp[s];
    int* op = idxOut + (size_t)row * KK;
    for (int s = 0; s < KK; ++s) {
        unsigned long long m = k[0];
        unsigned long long o1 = __shfl_xor(m, 1);
        m = (o1 > m) ? o1 : m;
        if (q == 0) op[s] = (int)(~(unsigned int)m);
        bool win = (k[0] == m);
#pragma unroll
        for (int qq = 0; qq < KK - 1; ++qq) k[qq] = win ? k[qq + 1] : k[qq];
        k[KK - 1] = win ? 0ull : k[KK - 1];
    }
}

// ------- 128x128 tiled fp32 GEMM with fused Wa/(Wb-Wa) transform:
// out[M, 2O]: out[:,o]=F·Wa[o]  out[:,O+o]=F·(Wb[o]-Wa[o]);  W is (O, 2K) raw.
__global__ __launch_bounds__(256) void gemm_yz(const float* __restrict__ F, int stride, int off,
                                               const float* __restrict__ W, int K, int O,
                                               float* __restrict__ out) {
    __shared__ float As[128 * 36];
    __shared__ float Ws[128 * 36];
    const int t = threadIdx.x;
    const int row0 = blockIdx.x * 128;
    const int col0 = blockIdx.y * 128;
    const int OC = 2 * O;
    float acc[8][8];
#pragma unroll
    for (int i = 0; i < 8; ++i)
#pragma unroll
        for (int j = 0; j < 8; ++j) acc[i][j] = 0.f;

    for (int kt = 0; kt < K; kt += 32) {
        __syncthreads();
        for (int i = t; i < 128 * 32; i += 256) {
            int r = i >> 5, c = i & 31;
            int k = kt + c;
            As[r * 36 + c] = (k < K) ? F[(size_t)(row0 + r) * stride + off + k] : 0.f;
            float wv = 0.f;
            if (k < K) {
                int o2 = col0 + r;
                if (o2 < O) wv = W[(size_t)o2 * 2 * K + k];
                else wv = W[(size_t)(o2 - O) * 2 * K + K + k] - W[(size_t)(o2 - O) * 2 * K + k];
            }
            Ws[r * 36 + c] = wv;
        }
        __syncthreads();
        const int r0 = t & 15, c0 = t >> 4;
        const float4* As4 = reinterpret_cast<const float4*>(As);
        const float4* Ws4 = reinterpret_cast<const float4*>(Ws);
#pragma unroll
        for (int k4 = 0; k4 < 8; ++k4) {
            float4 a[8], w[8];
#pragma unroll
            for (int i = 0; i < 8; ++i) a[i] = As4[(r0 + 16 * i) * 9 + k4];
#pragma unroll
            for (int j = 0; j < 8; ++j) w[j] = Ws4[(c0 + 16 * j) * 9 + k4];
#pragma unroll
            for (int i = 0; i < 8; ++i)
#pragma unroll
                for (int j = 0; j < 8; ++j) {
                    acc[i][j] += a[i].x * w[j].x;
                    acc[i][j] += a[i].y * w[j].y;
                    acc[i][j] += a[i].z * w[j].z;
                    acc[i][j] += a[i].w * w[j].w;
                }
        }
    }
    const int r0 = t & 15, c0 = t >> 4;
#pragma unroll
    for (int i = 0; i < 8; ++i)
#pragma unroll
        for (int j = 0; j < 8; ++j)
            out[(size_t)(row0 + r0 + 16 * i) * OC + col0 + c0 + 16 * j] = acc[i][j];
}

// ---------------- neighbor gather-max + affine + lrelu -> cat column block ----------------
__global__ __launch_bounds__(256) void neighbor_max(const float* __restrict__ yz,
                                                    const int* __restrict__ idx,
                                                    const float* __restrict__ g,
                                                    const float* __restrict__ bia, int O,
                                                    int outOff, float* __restrict__ cat) {
    int t = blockIdx.x * 256 + threadIdx.x;
    int og = O >> 2;
    if (t >= BB * NN * og) return;
    int o4 = t % og;
    int pn = t / og;
    int bbase = (pn >> 11) << 11;  // batch base row
    const int* ip = idx + (size_t)pn * KK;
    int O2 = O * 2;
    float mx = -INFINITY, my = -INFINITY, mz = -INFINITY, mw = -INFINITY;
    for (int j = 0; j < KK; ++j) {
        int nb = ip[j];
        const float4 v =
            *reinterpret_cast<const float4*>(yz + (size_t)(bbase + nb) * O2 + (o4 << 2));
        mx = fmaxf(mx, v.x); my = fmaxf(my, v.y); mz = fmaxf(mz, v.z); mw = fmaxf(mw, v.w);
    }
    const float4 z = *reinterpret_cast<const float4*>(yz + (size_t)pn * O2 + O + (o4 << 2));
    int o = o4 << 2;
    const float inv = 1.f / sqrtf(1.f + 1e-5f);
    float4 r;
    r.x = lrelu((mx + z.x) * (g[o + 0] * inv) + bia[o + 0]);
    r.y = lrelu((my + z.y) * (g[o + 1] * inv) + bia[o + 1]);
    r.z = lrelu((mz + z.z) * (g[o + 2] * inv) + bia[o + 2]);
    r.w = lrelu((mw + z.w) * (g[o + 3] * inv) + bia[o + 3]);
    *reinterpret_cast<float4*>(cat + (size_t)pn * 512 + outOff + o) = r;
}

// ---------------- final conv (K=512 -> 1024) + affine + lrelu + max over 128-point tile -----
__global__ __launch_bounds__(256) void final_gemm_max(const float* __restrict__ A,
                                                      const float* __restrict__ W,
                                                      const float* __restrict__ g,
                                                      const float* __restrict__ bia,
                                                      float* __restrict__ partial) {
    __shared__ float As[128 * 36];
    __shared__ float Ws[128 * 36];
    __shared__ float red[16 * 132];
    const int t = threadIdx.x;
    const int row0 = blockIdx.x * 128;  // global point row (batches contiguous)
    const int col0 = blockIdx.y * 128;
    float acc[8][8];
#pragma unroll
    for (int i = 0; i < 8; ++i)
#pragma unroll
        for (int j = 0; j < 8; ++j) acc[i][j] = 0.f;

    for (int kt = 0; kt < 512; kt += 32) {
        __syncthreads();
        for (int i = t; i < 128 * 32; i += 256) {
            int r = i >> 5, c = i & 31;
            int k = kt + c;
            As[r * 36 + c] = A[(size_t)(row0 + r) * 512 + k];
            Ws[r * 36 + c] = W[(size_t)(col0 + r) * 512 + k];
        }
        __syncthreads();
        const int r0 = t & 15, c0 = t >> 4;
        const float4* As4 = reinterpret_cast<const float4*>(As);
        const float4* Ws4 = reinterpret_cast<const float4*>(Ws);
#pragma unroll
        for (int k4 = 0; k4 < 8; ++k4) {
            float4 a[8], w[8];
#pragma unroll
            for (int i = 0; i < 8; ++i) a[i] = As4[(r0 + 16 * i) * 9 + k4];
#pragma unroll
            for (int j = 0; j < 8; ++j) w[j] = Ws4[(c0 + 16 * j) * 9 + k4];
#pragma unroll
            for (int i = 0; i < 8; ++i)
#pragma unroll
                for (int j = 0; j < 8; ++j) {
                    acc[i][j] += a[i].x * w[j].x;
                    acc[i][j] += a[i].y * w[j].y;
                    acc[i][j] += a[i].z * w[j].z;
                    acc[i][j] += a[i].w * w[j].w;
                }
        }
    }
    const int r0 = t & 15, c0 = t >> 4;
    const float inv = 1.f / sqrtf(1.f + 1e-5f);
#pragma unroll
    for (int j = 0; j < 8; ++j) {
        int o = col0 + c0 + 16 * j;
        float s = g[o] * inv;
        float bb = bia[o];
        float cm = -INFINITY;
#pragma unroll
        for (int i = 0; i < 8; ++i) {
            float h = acc[i][j] * s + bb;
            h = lrelu(h);
            cm = fmaxf(cm, h);
        }
        red[r0 * 132 + c0 + 16 * j] = cm;
    }
    __syncthreads();
    if (t < 128) {
        float m = -INFINITY;
        for (int q = 0; q < 16; ++q) m = fmaxf(m, red[q * 132 + t]);
        partial[(size_t)blockIdx.x * 1024 + col0 + t] = m;
    }
}

__global__ __launch_bounds__(256) void final_reduce(const float* __restrict__ partial,
                                                    float* __restrict__ out) {
    int t = blockIdx.x * 256 + threadIdx.x;
    if (t >= BB * 1024) return;
    int b = t >> 10, o = t & 1023;
    float m = -INFINITY;
    for (int q = 0; q < 16; ++q) m = fmaxf(m, partial[(size_t)(b * 16 + q) * 1024 + o]);
    out[t] = m;
}

extern "C" void kernel_launch(void* const* d_in, const int* in_sizes, int n_in, void* d_out,
                              int out_size, void* d_ws, size_t ws_size, hipStream_t stream) {
    const float* x  = (const float*)d_in[0];
    const float* W1 = (const float*)d_in[1];
    const float* W2 = (const float*)d_in[2];
    const float* W3 = (const float*)d_in[3];
    const float* W4 = (const float*)d_in[4];
    const float* W5 = (const float*)d_in[5];
    const float* g1 = (const float*)d_in[6];  const float* b1 = (const float*)d_in[7];
    const float* g2 = (const float*)d_in[8];  const float* b2 = (const float*)d_in[9];
    const float* g3 = (const float*)d_in[10]; const float* b3 = (const float*)d_in[11];
    const float* g4 = (const float*)d_in[12]; const float* b4 = (const float*)d_in[13];
    const float* g5 = (const float*)d_in[14]; const float* b5 = (const float*)d_in[15];

    float* ws   = (float*)d_ws;
    float* xt   = ws;                      // B*N*4          = 65536
    float* cat  = xt + 65536;              // B*N*512        = 8388608
    float* yz   = cat + 8388608;           // B*N*512        = 8388608
    float* xxb  = yz + 8388608;            // B*N            = 16384
    int*   idxb = (int*)(xxb + 16384);     // B*N*20         = 327680
    float* part = (float*)(idxb + 327680); // 128*1024       = 131072
    // knn partial lists alias yz (live only between knn_kernel and knn_merge;
    // yz is written by gemm_yz strictly after knn_merge each layer)
    unsigned long long* knnp = (unsigned long long*)yz;  // 16384*2*20 u64 = 5.2 MB

    dim3 blk(256);

    transpose_x<<<dim3(64), blk, 0, stream>>>(x, xt);

    // ---- layer 1: C=3 (xt, stride 4), O=64 -> cat[0..64)
    xx_kernel<<<dim3(64), blk, 0, stream>>>(xt, 4, 0, 3, xxb);
    knn_kernel<3><<<dim3(1024), blk, 0, stream>>>(xt, 4, 0, xxb, knnp);
    knn_merge<<<dim3(128), blk, 0, stream>>>(knnp, idxb);
    gemm_yz<<<dim3(128, 1), blk, 0, stream>>>(xt, 4, 0, W1, 3, 64, yz);
    neighbor_max<<<dim3(1024), blk, 0, stream>>>(yz, idxb, g1, b1, 64, 0, cat);

    // ---- layer 2: C=64 (cat off 0), O=64 -> cat[64..128)
    xx_kernel<<<dim3(64), blk, 0, stream>>>(cat, 512, 0, 64, xxb);
    knn_kernel<64><<<dim3(1024), blk, 0, stream>>>(cat, 512, 0, xxb, knnp);
    knn_merge<<<dim3(128), blk, 0, stream>>>(knnp, idxb);
    gemm_yz<<<dim3(128, 1), blk, 0, stream>>>(cat, 512, 0, W2, 64, 64, yz);
    neighbor_max<<<dim3(1024), blk, 0, stream>>>(yz, idxb, g2, b2, 64, 64, cat);

    // ---- layer 3: C=64 (cat off 64), O=128 -> cat[128..256)
    xx_kernel<<<dim3(64), blk, 0, stream>>>(cat, 512, 64, 64, xxb);
    knn_kernel<64><<<dim3(1024), blk, 0, stream>>>(cat, 512, 64, xxb, knnp);
    knn_merge<<<dim3(128), blk, 0, stream>>>(knnp, idxb);
    gemm_yz<<<dim3(128, 2), blk, 0, stream>>>(cat, 512, 64, W3, 64, 128, yz);
    neighbor_max<<<dim3(2048), blk, 0, stream>>>(yz, idxb, g3, b3, 128, 128, cat);

    // ---- layer 4: C=128 (cat off 128), O=256 -> cat[256..512)
    xx_kernel<<<dim3(64), blk, 0, stream>>>(cat, 512, 128, 128, xxb);
    knn_kernel<128><<<dim3(1024), blk, 0, stream>>>(cat, 512, 128, xxb, knnp);
    knn_merge<<<dim3(128), blk, 0, stream>>>(knnp, idxb);
    gemm_yz<<<dim3(128, 4), blk, 0, stream>>>(cat, 512, 128, W4, 128, 256, yz);
    neighbor_max<<<dim3(4096), blk, 0, stream>>>(yz, idxb, g4, b4, 256, 256, cat);

    // ---- final: 512 -> 1024 conv + lrelu + global max over N
    final_gemm_max<<<dim3(128, 8), blk, 0, stream>>>(cat, W5, g5, b5, part);
    final_reduce<<<dim3(32), blk, 0, stream>>>(part, (float*)d_out);
}